// Round 1
// baseline (221.654 us; speedup 1.0000x reference)
//
#include <hip/hip_runtime.h>

typedef __attribute__((ext_vector_type(4))) float floatx4;
typedef __attribute__((ext_vector_type(8))) __bf16 bf16x8;
typedef __attribute__((ext_vector_type(4))) __bf16 bf16x4;

#define K_DIM 2048
#define NH 96
#define M_ROWS 16384

// --- Kernel 1: convert W (96x2048 fp32) -> bf16 in workspace (RNE via __bf16 cast) ---
__global__ __launch_bounds__(256) void wconv_kernel(const float* __restrict__ W,
                                                    __bf16* __restrict__ Wb) {
    int i = (blockIdx.x * 256 + threadIdx.x) * 4;
    float4 v = *(const float4*)(W + i);
    bf16x4 o;
    o[0] = (__bf16)v.x; o[1] = (__bf16)v.y; o[2] = (__bf16)v.z; o[3] = (__bf16)v.w;
    *(bf16x4*)(Wb + i) = o;
}

// --- Kernel 2: skinny GEMM. One wave = 16 rows x 96 heads, K-loop in 64-slabs,
// double-buffered register prefetch, mfma_f32_16x16x32_bf16. ---
__global__ __launch_bounds__(64) void mh_gemm_kernel(const float* __restrict__ x,
                                                     const __bf16* __restrict__ Wb,
                                                     const float* __restrict__ bias,
                                                     float* __restrict__ out) {
    const int lane  = threadIdx.x;   // 0..63
    const int n15   = lane & 15;     // A: row m ; B: col n ; C: col n
    const int quad  = lane >> 4;     // 0..3
    const int mbase = blockIdx.x * 16;

    // A[m=lane&15][k=quad*8+j] ; B[k=quad*8+j][n=lane&15] (W row-major, k-contiguous)
    const float*  xptr = x  + (size_t)(mbase + n15) * K_DIM + quad * 8;
    const __bf16* wptr = Wb + (size_t)n15 * K_DIM + quad * 8;

    floatx4 acc[6] = {};

    float4 pa[4];   // prefetch: 16 fp32 of x (two K=32 A-frags)
    uint4  pb[12];  // prefetch: 12 bf16x8 B-frags (6 N-tiles x 2 K-frags)

    auto load_tile = [&](int k0, float4* a, uint4* b) {
        const float* xp = xptr + k0;
        a[0] = *(const float4*)(xp + 0);
        a[1] = *(const float4*)(xp + 4);
        a[2] = *(const float4*)(xp + 32);
        a[3] = *(const float4*)(xp + 36);
        const __bf16* wp = wptr + k0;
#pragma unroll
        for (int t = 0; t < 6; ++t) {
            b[t]     = *(const uint4*)(wp + (size_t)t * 16 * K_DIM);
            b[6 + t] = *(const uint4*)(wp + (size_t)t * 16 * K_DIM + 32);
        }
    };

    auto compute = [&](const float4* a, const uint4* b) {
        bf16x8 a0, a1;
        a0[0] = (__bf16)a[0].x; a0[1] = (__bf16)a[0].y;
        a0[2] = (__bf16)a[0].z; a0[3] = (__bf16)a[0].w;
        a0[4] = (__bf16)a[1].x; a0[5] = (__bf16)a[1].y;
        a0[6] = (__bf16)a[1].z; a0[7] = (__bf16)a[1].w;
        a1[0] = (__bf16)a[2].x; a1[1] = (__bf16)a[2].y;
        a1[2] = (__bf16)a[2].z; a1[3] = (__bf16)a[2].w;
        a1[4] = (__bf16)a[3].x; a1[5] = (__bf16)a[3].y;
        a1[6] = (__bf16)a[3].z; a1[7] = (__bf16)a[3].w;
#pragma unroll
        for (int t = 0; t < 6; ++t) {
            acc[t] = __builtin_amdgcn_mfma_f32_16x16x32_bf16(
                a0, __builtin_bit_cast(bf16x8, b[t]), acc[t], 0, 0, 0);
            acc[t] = __builtin_amdgcn_mfma_f32_16x16x32_bf16(
                a1, __builtin_bit_cast(bf16x8, b[6 + t]), acc[t], 0, 0, 0);
        }
    };

    load_tile(0, pa, pb);
    for (int k0 = 0; k0 < K_DIM - 64; k0 += 64) {
        float4 ca[4];
        uint4  cb[12];
#pragma unroll
        for (int i = 0; i < 4; ++i) ca[i] = pa[i];
#pragma unroll
        for (int i = 0; i < 12; ++i) cb[i] = pb[i];
        load_tile(k0 + 64, pa, pb);   // prefetch next slab while computing this one
        compute(ca, cb);
    }
    compute(pa, pb);

    // C/D layout: col(n) = lane&15, row(m) = quad*4 + reg  [m89-verified]
    const int orow = mbase + quad * 4;
#pragma unroll
    for (int t = 0; t < 6; ++t) {
        const int h = t * 16 + n15;
        const float bv = bias[h];
#pragma unroll
        for (int r = 0; r < 4; ++r) {
            out[(size_t)(orow + r) * NH + h] = acc[t][r] + bv;
        }
    }
}

extern "C" void kernel_launch(void* const* d_in, const int* in_sizes, int n_in,
                              void* d_out, int out_size, void* d_ws, size_t ws_size,
                              hipStream_t stream) {
    const float* x = (const float*)d_in[0];
    const float* W = (const float*)d_in[1];
    const float* b = (const float*)d_in[2];
    float* out = (float*)d_out;
    __bf16* Wb = (__bf16*)d_ws;   // 96*2048*2 = 393216 bytes of workspace

    wconv_kernel<<<(NH * K_DIM / 4) / 256, 256, 0, stream>>>(W, Wb);
    mh_gemm_kernel<<<M_ROWS / 16, 64, 0, stream>>>(x, Wb, b, out);
}

// Round 2
// 217.373 us; speedup vs baseline: 1.0197x; 1.0197x over previous
//
#include <hip/hip_runtime.h>

typedef __attribute__((ext_vector_type(4))) float floatx4;
typedef __attribute__((ext_vector_type(8))) __bf16 bf16x8;
typedef __attribute__((ext_vector_type(4))) __bf16 bf16x4;

#define K_DIM 2048
#define NH 96
#define M_ROWS 16384
#define KSPLIT 4
#define KCHUNK (K_DIM / KSPLIT)   // 512 per wave

// --- Kernel 1: convert W (96x2048 fp32) -> bf16 in workspace (RNE) ---
__global__ __launch_bounds__(256) void wconv_kernel(const float* __restrict__ W,
                                                    __bf16* __restrict__ Wb) {
    int i = (blockIdx.x * 256 + threadIdx.x) * 4;
    float4 v = *(const float4*)(W + i);
    bf16x4 o;
    o[0] = (__bf16)v.x; o[1] = (__bf16)v.y; o[2] = (__bf16)v.z; o[3] = (__bf16)v.w;
    *(bf16x4*)(Wb + i) = o;
}

// --- Kernel 2: skinny GEMM, K-split x4 within a block.
// Each wave: 16 rows x 96 heads over K=512, register double-buffered prefetch,
// mfma_f32_16x16x32_bf16. LDS reduction across the 4 waves, wave 0 stores. ---
__global__ __launch_bounds__(256, 4) void mh_gemm_kernel(const float* __restrict__ x,
                                                         const __bf16* __restrict__ Wb,
                                                         const float* __restrict__ bias,
                                                         float* __restrict__ out) {
    const int tid   = threadIdx.x;
    const int wave  = tid >> 6;      // 0..3 -> K chunk
    const int lane  = tid & 63;
    const int n15   = lane & 15;     // A: row m ; B/C: col n
    const int quad  = lane >> 4;     // 0..3
    const int mbase = blockIdx.x * 16;
    const int kbase = wave * KCHUNK;

    // A[m=lane&15][k=quad*8+j] ; B[k=quad*8+j][n=lane&15] (W row-major, k-contig)
    const float*  xptr = x  + (size_t)(mbase + n15) * K_DIM + kbase + quad * 8;
    const __bf16* wptr = Wb + (size_t)n15 * K_DIM + kbase + quad * 8;

    floatx4 acc[6] = {};

    float4 pa[4];   // prefetch: 16 fp32 of x (two K=32 A-frags)
    uint4  pb[12];  // prefetch: 12 bf16x8 B-frags (6 N-tiles x 2 K-frags)

    auto load_tile = [&](int k0, float4* a, uint4* b) {
        const float* xp = xptr + k0;
        a[0] = *(const float4*)(xp + 0);
        a[1] = *(const float4*)(xp + 4);
        a[2] = *(const float4*)(xp + 32);
        a[3] = *(const float4*)(xp + 36);
        const __bf16* wp = wptr + k0;
#pragma unroll
        for (int t = 0; t < 6; ++t) {
            b[t]     = *(const uint4*)(wp + (size_t)t * 16 * K_DIM);
            b[6 + t] = *(const uint4*)(wp + (size_t)t * 16 * K_DIM + 32);
        }
    };

    auto compute = [&](const float4* a, const uint4* b) {
        bf16x8 a0, a1;
        a0[0] = (__bf16)a[0].x; a0[1] = (__bf16)a[0].y;
        a0[2] = (__bf16)a[0].z; a0[3] = (__bf16)a[0].w;
        a0[4] = (__bf16)a[1].x; a0[5] = (__bf16)a[1].y;
        a0[6] = (__bf16)a[1].z; a0[7] = (__bf16)a[1].w;
        a1[0] = (__bf16)a[2].x; a1[1] = (__bf16)a[2].y;
        a1[2] = (__bf16)a[2].z; a1[3] = (__bf16)a[2].w;
        a1[4] = (__bf16)a[3].x; a1[5] = (__bf16)a[3].y;
        a1[6] = (__bf16)a[3].z; a1[7] = (__bf16)a[3].w;
#pragma unroll
        for (int t = 0; t < 6; ++t) {
            acc[t] = __builtin_amdgcn_mfma_f32_16x16x32_bf16(
                a0, __builtin_bit_cast(bf16x8, b[t]), acc[t], 0, 0, 0);
            acc[t] = __builtin_amdgcn_mfma_f32_16x16x32_bf16(
                a1, __builtin_bit_cast(bf16x8, b[6 + t]), acc[t], 0, 0, 0);
        }
    };

    load_tile(0, pa, pb);
    for (int k0 = 0; k0 < KCHUNK - 64; k0 += 64) {   // 7 iters; slab 448 in tail
        float4 ca[4];
        uint4  cb[12];
#pragma unroll
        for (int i = 0; i < 4; ++i) ca[i] = pa[i];
#pragma unroll
        for (int i = 0; i < 12; ++i) cb[i] = pb[i];
        load_tile(k0 + 64, pa, pb);   // prefetch next slab while computing this one
        compute(ca, cb);
    }
    compute(pa, pb);

    // --- cross-wave K reduction via LDS. Stride 25 floats -> conflict-free. ---
    __shared__ float red[KSPLIT - 1][64][25];
    if (wave > 0) {
#pragma unroll
        for (int t = 0; t < 6; ++t)
#pragma unroll
            for (int r = 0; r < 4; ++r)
                red[wave - 1][lane][t * 4 + r] = acc[t][r];
    }
    __syncthreads();

    if (wave == 0) {
#pragma unroll
        for (int w = 0; w < KSPLIT - 1; ++w)
#pragma unroll
            for (int t = 0; t < 6; ++t)
#pragma unroll
                for (int r = 0; r < 4; ++r)
                    acc[t][r] += red[w][lane][t * 4 + r];

        // C/D layout: col(n) = lane&15, row(m) = quad*4 + reg  [m89-verified]
        const int orow = mbase + quad * 4;
#pragma unroll
        for (int t = 0; t < 6; ++t) {
            const int h = t * 16 + n15;
            const float bv = bias[h];
#pragma unroll
            for (int r = 0; r < 4; ++r) {
                out[(size_t)(orow + r) * NH + h] = acc[t][r] + bv;
            }
        }
    }
}

extern "C" void kernel_launch(void* const* d_in, const int* in_sizes, int n_in,
                              void* d_out, int out_size, void* d_ws, size_t ws_size,
                              hipStream_t stream) {
    const float* x = (const float*)d_in[0];
    const float* W = (const float*)d_in[1];
    const float* b = (const float*)d_in[2];
    float* out = (float*)d_out;
    __bf16* Wb = (__bf16*)d_ws;   // 96*2048*2 = 393216 bytes of workspace

    wconv_kernel<<<(NH * K_DIM / 4) / 256, 256, 0, stream>>>(W, Wb);
    mh_gemm_kernel<<<M_ROWS / 16, 256, 0, stream>>>(x, Wb, b, out);
}

// Round 3
// 208.124 us; speedup vs baseline: 1.0650x; 1.0444x over previous
//
#include <hip/hip_runtime.h>
#include <stdint.h>

typedef __attribute__((ext_vector_type(4))) float floatx4;
typedef __attribute__((ext_vector_type(8))) __bf16 bf16x8;

#define K_DIM 2048
#define NH 96
#define M_ROWS 16384
#define BK 64
#define NSLAB (K_DIM / BK)             // 32
#define KSPLIT 2
#define SLAB_PER_BLK (NSLAB / KSPLIT)  // 16
#define WSLAB_BYTES (NH * BK * 2)      // 12288 B per K-slab of packed W
#define WPACK_BYTES (NSLAB * WSLAB_BYTES)  // 393216

// async global->LDS, 16B per lane; LDS dest = wave-uniform base + lane*16
#define GLD16(gp, lp) __builtin_amdgcn_global_load_lds( \
    (const __attribute__((address_space(1))) uint32_t*)(gp), \
    (__attribute__((address_space(3))) uint32_t*)(lp), 16, 0, 0)

// --- Kernel 1: pack W (96x2048 fp32) into bf16 B-fragments in slab order.
// Layout: [slab s][frag f(2)][t(6)][lane(64)][16B], frag elem j = W[t*16+(l&15)][s*64+f*32+(l>>4)*8+j]
__global__ __launch_bounds__(256) void wpack_kernel(const float* __restrict__ W,
                                                    uint8_t* __restrict__ WbF) {
    int u = blockIdx.x * 256 + threadIdx.x;   // 0 .. 24576 = 384 frags * 64 lanes
    int l  = u & 63;
    int fr = u >> 6;            // fr = s*12 + f*6 + t
    int t  = fr % 6;
    int f  = (fr / 6) & 1;
    int s  = fr / 12;
    int head = t * 16 + (l & 15);
    int k    = s * 64 + f * 32 + (l >> 4) * 8;
    const float* wp = W + (size_t)head * K_DIM + k;
    float4 v0 = *(const float4*)wp;
    float4 v1 = *(const float4*)(wp + 4);
    bf16x8 o;
    o[0] = (__bf16)v0.x; o[1] = (__bf16)v0.y; o[2] = (__bf16)v0.z; o[3] = (__bf16)v0.w;
    o[4] = (__bf16)v1.x; o[5] = (__bf16)v1.y; o[6] = (__bf16)v1.z; o[7] = (__bf16)v1.w;
    *(bf16x8*)(WbF + (size_t)u * 16) = o;     // u*16 == fr*1024 + l*16
}

// --- Kernel 2: LDS-staged GEMM. Block: 4 waves, M-tile 64, K-range 1024 (KSPLIT=2),
// BK=64 slabs, double-buffered LDS, global_load_lds staging, XOR-swizzled x tile. ---
__global__ __launch_bounds__(256, 2) void mh_gemm_kernel(const float* __restrict__ x,
                                                         const uint8_t* __restrict__ WbF,
                                                         float* __restrict__ partial) {
    __shared__ __align__(16) float   xs[2][64 * 64];        // 2 x 16 KB
    __shared__ __align__(16) uint8_t wsm[2][WSLAB_BYTES];   // 2 x 12 KB

    const int tid  = threadIdx.x;
    const int w    = tid >> 6;
    const int lane = tid & 63;
    const int n15  = lane & 15;
    const int quad = lane >> 4;
    const int kb   = blockIdx.x & 1;
    const int m0   = (int)(blockIdx.x >> 1) * 64;
    const int s0   = kb * SLAB_PER_BLK;

    const int rsub = lane >> 4;   // staging: row within 4-row group
    const int cst  = lane & 15;   // staging: LDS chunk slot

    auto stage = [&](int s, int b) {
        // x tile: 64 rows x 64 floats, row-major 256B rows, chunk slot = chunk ^ (row&15)
        const float* xg = x + (size_t)m0 * K_DIM + (size_t)(s0 + s) * BK;
#pragma unroll
        for (int p = 0; p < 4; ++p) {
            int R     = p * 16 + w * 4 + rsub;
            int chunk = cst ^ (R & 15);
            GLD16(xg + (size_t)R * K_DIM + chunk * 4,
                  &xs[b][(p * 16 + w * 4) * 64]);          // uniform base; +lane*16 implicit
        }
        // W slab: contiguous 12 KB copy
        const uint8_t* wg = WbF + (size_t)(s0 + s) * WSLAB_BYTES;
#pragma unroll
        for (int p = 0; p < 3; ++p) {
            GLD16(wg + p * 4096 + w * 1024 + lane * 16,
                  &wsm[b][p * 4096 + w * 1024]);
        }
    };

    floatx4 acc[6] = {};

    auto compute = [&](int b) {
        float4 a[2][2];
#pragma unroll
        for (int f = 0; f < 2; ++f)
#pragma unroll
            for (int h = 0; h < 2; ++h) {
                int cc   = f * 8 + quad * 2 + h;
                int slot = cc ^ n15;
                a[f][h] = *(const float4*)&xs[b][(w * 16 + n15) * 64 + slot * 4];
            }
        bf16x8 a0, a1;
        a0[0] = (__bf16)a[0][0].x; a0[1] = (__bf16)a[0][0].y;
        a0[2] = (__bf16)a[0][0].z; a0[3] = (__bf16)a[0][0].w;
        a0[4] = (__bf16)a[0][1].x; a0[5] = (__bf16)a[0][1].y;
        a0[6] = (__bf16)a[0][1].z; a0[7] = (__bf16)a[0][1].w;
        a1[0] = (__bf16)a[1][0].x; a1[1] = (__bf16)a[1][0].y;
        a1[2] = (__bf16)a[1][0].z; a1[3] = (__bf16)a[1][0].w;
        a1[4] = (__bf16)a[1][1].x; a1[5] = (__bf16)a[1][1].y;
        a1[6] = (__bf16)a[1][1].z; a1[7] = (__bf16)a[1][1].w;
#pragma unroll
        for (int t = 0; t < 6; ++t) {
            uint4 b0 = *(const uint4*)&wsm[b][(0 * 6 + t) * 1024 + lane * 16];
            uint4 b1 = *(const uint4*)&wsm[b][(1 * 6 + t) * 1024 + lane * 16];
            acc[t] = __builtin_amdgcn_mfma_f32_16x16x32_bf16(
                a0, __builtin_bit_cast(bf16x8, b0), acc[t], 0, 0, 0);
            acc[t] = __builtin_amdgcn_mfma_f32_16x16x32_bf16(
                a1, __builtin_bit_cast(bf16x8, b1), acc[t], 0, 0, 0);
        }
    };

    stage(0, 0);
    for (int s = 0; s < SLAB_PER_BLK; ++s) {
        __builtin_amdgcn_s_waitcnt(0);   // drain stage(s) (vmcnt) before barrier
        __syncthreads();                 // all waves' slab-s data resident; prev buffer free
        if (s + 1 < SLAB_PER_BLK) stage(s + 1, (s + 1) & 1);  // overlaps compute(s)
        compute(s & 1);
    }

    // epilogue: partial[kb][row][head]; C/D layout col=n15, row=quad*4+reg [m89]
    float* P = partial + (size_t)kb * M_ROWS * NH;
    const int orow = m0 + w * 16 + quad * 4;
#pragma unroll
    for (int t = 0; t < 6; ++t) {
        const int hcol = t * 16 + n15;
#pragma unroll
        for (int r = 0; r < 4; ++r)
            P[(size_t)(orow + r) * NH + hcol] = acc[t][r];
    }
}

// --- Kernel 3: out = P0 + P1 + bias ---
__global__ __launch_bounds__(256) void reduce_kernel(const float* __restrict__ P,
                                                     const float* __restrict__ bias,
                                                     float* __restrict__ out) {
    int i = blockIdx.x * 256 + threadIdx.x;      // float4 index, 393216 total
    float4 p0 = *(const float4*)(P + (size_t)i * 4);
    float4 p1 = *(const float4*)(P + (size_t)M_ROWS * NH + (size_t)i * 4);
    float4 bv = *(const float4*)(bias + (i % 24) * 4);
    float4 o;
    o.x = p0.x + p1.x + bv.x;
    o.y = p0.y + p1.y + bv.y;
    o.z = p0.z + p1.z + bv.z;
    o.w = p0.w + p1.w + bv.w;
    *(float4*)(out + (size_t)i * 4) = o;
}

extern "C" void kernel_launch(void* const* d_in, const int* in_sizes, int n_in,
                              void* d_out, int out_size, void* d_ws, size_t ws_size,
                              hipStream_t stream) {
    const float* x = (const float*)d_in[0];
    const float* W = (const float*)d_in[1];
    const float* b = (const float*)d_in[2];
    float* out = (float*)d_out;

    uint8_t* WbF    = (uint8_t*)d_ws;                       // 393216 B
    float*   Ppart  = (float*)((uint8_t*)d_ws + WPACK_BYTES);  // 2 * 16384 * 96 * 4 B

    wpack_kernel<<<96, 256, 0, stream>>>(W, WbF);
    mh_gemm_kernel<<<(M_ROWS / 64) * KSPLIT, 256, 0, stream>>>(x, WbF, Ppart);
    reduce_kernel<<<(M_ROWS * NH / 4) / 256, 256, 0, stream>>>(Ppart, b, out);
}

// Round 4
// 206.649 us; speedup vs baseline: 1.0726x; 1.0071x over previous
//
#include <hip/hip_runtime.h>
#include <stdint.h>

typedef __attribute__((ext_vector_type(4))) float floatx4;
typedef __attribute__((ext_vector_type(8))) __bf16 bf16x8;

#define K_DIM 2048
#define NH 96
#define M_ROWS 16384
#define KSPLIT 4
#define KRANGE (K_DIM / KSPLIT)            // 512 per block
#define BK 64
#define STEPS (KRANGE / BK)                // 8
#define NSLAB (K_DIM / BK)                 // 32
#define WSLAB_BYTES (NH * BK * 2)          // 12288 B per packed W slab
#define WPACK_BYTES (NSLAB * WSLAB_BYTES)  // 393216

// async global->LDS, 16B/lane; LDS dest = wave-uniform base (+ lane*16 implicit)
#define GLD16(gp, lp) __builtin_amdgcn_global_load_lds( \
    (const __attribute__((address_space(1))) uint32_t*)(gp), \
    (__attribute__((address_space(3))) uint32_t*)(lp), 16, 0, 0)

// --- Kernel 1: pack W (96x2048 fp32) into bf16 B-fragments, slab-major.
// Layout: [slab s][f(2)][t(6)][lane(64)][16B]; elem j = W[t*16+(l&15)][s*64+f*32+(l>>4)*8+j]
__global__ __launch_bounds__(256) void wpack_kernel(const float* __restrict__ W,
                                                    uint8_t* __restrict__ WbF) {
    int u = blockIdx.x * 256 + threadIdx.x;   // 0 .. 24576 = 384 frags * 64 lanes
    int l  = u & 63;
    int fr = u >> 6;            // fr = s*12 + f*6 + t
    int t  = fr % 6;
    int f  = (fr / 6) & 1;
    int s  = fr / 12;
    int head = t * 16 + (l & 15);
    int k    = s * 64 + f * 32 + (l >> 4) * 8;
    const float* wp = W + (size_t)head * K_DIM + k;
    float4 v0 = *(const float4*)wp;
    float4 v1 = *(const float4*)(wp + 4);
    bf16x8 o;
    o[0] = (__bf16)v0.x; o[1] = (__bf16)v0.y; o[2] = (__bf16)v0.z; o[3] = (__bf16)v0.w;
    o[4] = (__bf16)v1.x; o[5] = (__bf16)v1.y; o[6] = (__bf16)v1.z; o[7] = (__bf16)v1.w;
    *(bf16x8*)(WbF + (size_t)u * 16) = o;
}

// --- Kernel 2: skinny GEMM. x: direct global->VGPR A-frags (reg dbuf).
// W: LDS slab dbuf (24 KB). Block: 4 waves x 16 rows = 64-row M-tile, K=512.
// Grid 1024 = 256 M-tiles x 4 K-splits -> 4 blocks/CU, 16 waves/CU. ---
__global__ __launch_bounds__(256, 4) void mh_gemm_kernel(const float* __restrict__ x,
                                                         const uint8_t* __restrict__ WbF,
                                                         float* __restrict__ partial) {
    __shared__ __align__(16) uint8_t wsm[2][WSLAB_BYTES];   // 2 x 12 KB

    const int tid  = threadIdx.x;
    const int w    = tid >> 6;
    const int lane = tid & 63;
    const int n15  = lane & 15;
    const int quad = lane >> 4;
    const int kb   = blockIdx.x & (KSPLIT - 1);
    const int m0   = (int)(blockIdx.x >> 2) * 64;
    const int s0   = kb * STEPS;

    // A[m=n15][k=quad*8+j]: per row, 2x16B at stride-32 -> 2 lines/row, optimal
    const float* xptr = x + (size_t)(m0 + w * 16 + n15) * K_DIM
                          + (size_t)kb * KRANGE + quad * 8;

    auto stage_W = [&](int s, int b) {
        const uint8_t* wg = WbF + (size_t)(s0 + s) * WSLAB_BYTES + w * 3072;
        uint8_t* ls = &wsm[b][w * 3072];
        GLD16(wg + 0    + lane * 16, ls + 0);
        GLD16(wg + 1024 + lane * 16, ls + 1024);
        GLD16(wg + 2048 + lane * 16, ls + 2048);
    };

    auto load_x = [&](int s, float4* p) {
        const float* xp = xptr + s * BK;
        p[0] = *(const float4*)(xp + 0);
        p[1] = *(const float4*)(xp + 4);
        p[2] = *(const float4*)(xp + 32);
        p[3] = *(const float4*)(xp + 36);
    };

    floatx4 acc[6] = {};

    auto compute = [&](int b, const float4* p) {
        bf16x8 a0, a1;
        a0[0] = (__bf16)p[0].x; a0[1] = (__bf16)p[0].y;
        a0[2] = (__bf16)p[0].z; a0[3] = (__bf16)p[0].w;
        a0[4] = (__bf16)p[1].x; a0[5] = (__bf16)p[1].y;
        a0[6] = (__bf16)p[1].z; a0[7] = (__bf16)p[1].w;
        a1[0] = (__bf16)p[2].x; a1[1] = (__bf16)p[2].y;
        a1[2] = (__bf16)p[2].z; a1[3] = (__bf16)p[2].w;
        a1[4] = (__bf16)p[3].x; a1[5] = (__bf16)p[3].y;
        a1[6] = (__bf16)p[3].z; a1[7] = (__bf16)p[3].w;
#pragma unroll
        for (int t = 0; t < 6; ++t) {
            uint4 b0 = *(const uint4*)&wsm[b][(0 * 6 + t) * 1024 + lane * 16];
            uint4 b1 = *(const uint4*)&wsm[b][(1 * 6 + t) * 1024 + lane * 16];
            acc[t] = __builtin_amdgcn_mfma_f32_16x16x32_bf16(
                a0, __builtin_bit_cast(bf16x8, b0), acc[t], 0, 0, 0);
            acc[t] = __builtin_amdgcn_mfma_f32_16x16x32_bf16(
                a1, __builtin_bit_cast(bf16x8, b1), acc[t], 0, 0, 0);
        }
    };

    float4 pa[2][4];
    stage_W(0, 0);
    load_x(0, pa[0]);
    for (int s = 0; s < STEPS; ++s) {
        __builtin_amdgcn_s_waitcnt(0);   // drain W(s) staging (and x regs) pre-barrier
        __syncthreads();
        if (s + 1 < STEPS) {
            stage_W(s + 1, (s + 1) & 1); // overlaps compute(s)
            load_x(s + 1, pa[(s + 1) & 1]);
        }
        compute(s & 1, pa[s & 1]);
    }

    // partial[kb][row][head]; C/D: col=n15, row=quad*4+reg [m89-verified]
    float* P = partial + (size_t)kb * M_ROWS * NH;
    const int orow = m0 + w * 16 + quad * 4;
#pragma unroll
    for (int t = 0; t < 6; ++t) {
        const int hcol = t * 16 + n15;
#pragma unroll
        for (int r = 0; r < 4; ++r)
            P[(size_t)(orow + r) * NH + hcol] = acc[t][r];
    }
}

// --- Kernel 3: out = P0 + P1 + P2 + P3 + bias ---
__global__ __launch_bounds__(256) void reduce_kernel(const float* __restrict__ P,
                                                     const float* __restrict__ bias,
                                                     float* __restrict__ out) {
    const size_t stride = (size_t)M_ROWS * NH;
    int i = blockIdx.x * 256 + threadIdx.x;      // float4 index, 393216 total
    float4 p0 = *(const float4*)(P + (size_t)i * 4);
    float4 p1 = *(const float4*)(P + stride + (size_t)i * 4);
    float4 p2 = *(const float4*)(P + 2 * stride + (size_t)i * 4);
    float4 p3 = *(const float4*)(P + 3 * stride + (size_t)i * 4);
    float4 bv = *(const float4*)(bias + (i % 24) * 4);
    float4 o;
    o.x = p0.x + p1.x + p2.x + p3.x + bv.x;
    o.y = p0.y + p1.y + p2.y + p3.y + bv.y;
    o.z = p0.z + p1.z + p2.z + p3.z + bv.z;
    o.w = p0.w + p1.w + p2.w + p3.w + bv.w;
    *(float4*)(out + (size_t)i * 4) = o;
}

extern "C" void kernel_launch(void* const* d_in, const int* in_sizes, int n_in,
                              void* d_out, int out_size, void* d_ws, size_t ws_size,
                              hipStream_t stream) {
    const float* x = (const float*)d_in[0];
    const float* W = (const float*)d_in[1];
    const float* b = (const float*)d_in[2];
    float* out = (float*)d_out;

    uint8_t* WbF   = (uint8_t*)d_ws;                          // 393216 B
    float*   Ppart = (float*)((uint8_t*)d_ws + WPACK_BYTES);  // 4 * 16384*96*4 B

    wpack_kernel<<<96, 256, 0, stream>>>(W, WbF);
    mh_gemm_kernel<<<(M_ROWS / 64) * KSPLIT, 256, 0, stream>>>(x, WbF, Ppart);
    reduce_kernel<<<(M_ROWS * NH / 4) / 256, 256, 0, stream>>>(Ppart, b, out);
}

// Round 5
// 204.414 us; speedup vs baseline: 1.0843x; 1.0109x over previous
//
#include <hip/hip_runtime.h>
#include <stdint.h>

typedef __attribute__((ext_vector_type(4))) float floatx4;
typedef __attribute__((ext_vector_type(8))) __bf16 bf16x8;

#define K_DIM 2048
#define NH 96
#define M_ROWS 16384
#define KSPLIT 4
#define KRANGE (K_DIM / KSPLIT)        // 512 per block
#define BK 32
#define STEPS (KRANGE / BK)            // 16
#define NSLAB (K_DIM / BK)             // 64
#define WSLAB_PAD 8192                 // 6 KB real (6 frags) + 2 KB pad -> uniform 2 GLD16/wave
#define WPACK_BYTES (NSLAB * WSLAB_PAD)  // 524288

// async global->LDS, 16B/lane; LDS dest = wave-uniform base (+ lane*16 implicit)
#define GLD16(gp, lp) __builtin_amdgcn_global_load_lds( \
    (const __attribute__((address_space(1))) uint32_t*)(gp), \
    (__attribute__((address_space(3))) uint32_t*)(lp), 16, 0, 0)

// s_waitcnt imm: vmcnt [3:0], expcnt [6:4], lgkmcnt [11:8].
// Wait vmcnt(n) AND lgkmcnt(0) (cross-wave LDS hazard needs reads complete pre-barrier).
#define WAIT_VM_LGKM0(n) __builtin_amdgcn_s_waitcnt((0 << 8) | (7 << 4) | (n))

#define BARRIER() do { asm volatile("" ::: "memory"); \
                       __builtin_amdgcn_s_barrier();  \
                       asm volatile("" ::: "memory"); } while (0)

// --- Kernel 1: pack W into bf16 B-frags, BK=32 slabs, 8KB-padded slab stride.
// Frag (s,t), lane l, elem j = W[t*16+(l&15)][s*32+(l>>4)*8+j]
__global__ __launch_bounds__(256) void wpack_kernel(const float* __restrict__ W,
                                                    uint8_t* __restrict__ WbF) {
    int u = blockIdx.x * 256 + threadIdx.x;   // 0..24575 = 64 slabs * 6 frags * 64 lanes
    int l  = u & 63;
    int fr = u >> 6;
    int t  = fr % 6;
    int s  = fr / 6;
    int head = t * 16 + (l & 15);
    int k    = s * 32 + (l >> 4) * 8;
    const float* wp = W + (size_t)head * K_DIM + k;
    float4 v0 = *(const float4*)wp;
    float4 v1 = *(const float4*)(wp + 4);
    bf16x8 o;
    o[0] = (__bf16)v0.x; o[1] = (__bf16)v0.y; o[2] = (__bf16)v0.z; o[3] = (__bf16)v0.w;
    o[4] = (__bf16)v1.x; o[5] = (__bf16)v1.y; o[6] = (__bf16)v1.z; o[7] = (__bf16)v1.w;
    *(bf16x8*)(WbF + (size_t)s * WSLAB_PAD + t * 1024 + l * 16) = o;
}

// --- Kernel 2: fully-coalesced LDS-staged GEMM, fine-grained vmcnt pipeline.
// Block: 4 waves x M=32 = 128-row M-tile, K=512 (KSPLIT=4), BK=32, triple-buffer.
// Grid 512 -> 2 blocks/CU (LDS 72 KB). Each wave: 6 GLD16/slab (4 x + 2 W).
__global__ __launch_bounds__(256, 2) void mh_gemm_kernel(const float* __restrict__ x,
                                                         const uint8_t* __restrict__ WbF,
                                                         float* __restrict__ partial) {
    __shared__ __align__(16) float   xs[3][128 * 32];   // 3 x 16 KB, rows 128B, XOR-swizzled
    __shared__ __align__(16) uint8_t ws[3][WSLAB_PAD];  // 3 x 8 KB

    const int tid  = threadIdx.x;
    const int w    = tid >> 6;
    const int lane = tid & 63;
    const int n15  = lane & 15;
    const int quad = lane >> 4;
    const int kb   = blockIdx.x & (KSPLIT - 1);
    const int m0   = (int)(blockIdx.x >> 2) * 128;

    // x staging: lane -> (row = lane>>3, chunk); global chunk = (lane&7) ^ (row&7)
    // so LDS slot c of row r holds global chunk c ^ (r&7). Coalesced: 128B/row.
    const float* xg0 = x + (size_t)(m0 + w * 32 + (lane >> 3)) * K_DIM
                         + (size_t)kb * KRANGE
                         + (((lane & 7) ^ ((lane >> 3) & 7)) << 2);
    const uint8_t* wg0 = WbF + (size_t)(kb * STEPS) * WSLAB_PAD + (w * 2) * 1024 + lane * 16;

    auto stage = [&](int s, int b) {
        const float* xg = xg0 + s * BK;
        GLD16(xg,              &xs[b][(w * 32 +  0) * 32]);
        GLD16(xg +  8 * K_DIM, &xs[b][(w * 32 +  8) * 32]);
        GLD16(xg + 16 * K_DIM, &xs[b][(w * 32 + 16) * 32]);
        GLD16(xg + 24 * K_DIM, &xs[b][(w * 32 + 24) * 32]);
        const uint8_t* wg = wg0 + (size_t)s * WSLAB_PAD;
        GLD16(wg,        &ws[b][(w * 2) * 1024]);
        GLD16(wg + 1024, &ws[b][(w * 2 + 1) * 1024]);
    };

    floatx4 acc[2][6] = {};

    auto compute = [&](int b) {
        bf16x8 af[2];
#pragma unroll
        for (int h = 0; h < 2; ++h) {
            const int R = w * 32 + h * 16 + n15;
            const float* rowp = &xs[b][R * 32];
            const int sw = n15 & 7;
            float4 lo = *(const float4*)(rowp + (((quad * 2    ) ^ sw) << 2));
            float4 hi = *(const float4*)(rowp + (((quad * 2 + 1) ^ sw) << 2));
            bf16x8 a;
            a[0] = (__bf16)lo.x; a[1] = (__bf16)lo.y;
            a[2] = (__bf16)lo.z; a[3] = (__bf16)lo.w;
            a[4] = (__bf16)hi.x; a[5] = (__bf16)hi.y;
            a[6] = (__bf16)hi.z; a[7] = (__bf16)hi.w;
            af[h] = a;
        }
#pragma unroll
        for (int t = 0; t < 6; ++t) {
            uint4 bw = *(const uint4*)&ws[b][t * 1024 + lane * 16];
            bf16x8 bb = __builtin_bit_cast(bf16x8, bw);
            acc[0][t] = __builtin_amdgcn_mfma_f32_16x16x32_bf16(af[0], bb, acc[0][t], 0, 0, 0);
            acc[1][t] = __builtin_amdgcn_mfma_f32_16x16x32_bf16(af[1], bb, acc[1][t], 0, 0, 0);
        }
    };

    stage(0, 0);
    stage(1, 1);
    for (int s = 0; s < STEPS; ++s) {
        // steady state: allow the newest 6 loads (slab s+1) to stay in flight;
        // forces slab s complete. Tail: drain all.
        if (s < STEPS - 1) WAIT_VM_LGKM0(6);
        else               WAIT_VM_LGKM0(0);
        BARRIER();
        if (s + 2 < STEPS) stage(s + 2, (s + 2) % 3);  // buf (s+2)%3 == (s-1)%3, freed by barrier
        compute(s % 3);
    }

    // partial[kb][row][head]; C/D: col=n15, row=quad*4+reg [m89-verified]
    float* P = partial + (size_t)kb * M_ROWS * NH;
#pragma unroll
    for (int h = 0; h < 2; ++h) {
        const int orow = m0 + w * 32 + h * 16 + quad * 4;
#pragma unroll
        for (int t = 0; t < 6; ++t) {
            const int hcol = t * 16 + n15;
#pragma unroll
            for (int r = 0; r < 4; ++r)
                P[(size_t)(orow + r) * NH + hcol] = acc[h][t][r];
        }
    }
}

// --- Kernel 3: out = P0 + P1 + P2 + P3 + bias ---
__global__ __launch_bounds__(256) void reduce_kernel(const float* __restrict__ P,
                                                     const float* __restrict__ bias,
                                                     float* __restrict__ out) {
    const size_t stride = (size_t)M_ROWS * NH;
    int i = blockIdx.x * 256 + threadIdx.x;      // float4 index, 393216 total
    float4 p0 = *(const float4*)(P + (size_t)i * 4);
    float4 p1 = *(const float4*)(P + stride + (size_t)i * 4);
    float4 p2 = *(const float4*)(P + 2 * stride + (size_t)i * 4);
    float4 p3 = *(const float4*)(P + 3 * stride + (size_t)i * 4);
    float4 bv = *(const float4*)(bias + (i % 24) * 4);
    float4 o;
    o.x = p0.x + p1.x + p2.x + p3.x + bv.x;
    o.y = p0.y + p1.y + p2.y + p3.y + bv.y;
    o.z = p0.z + p1.z + p2.z + p3.z + bv.z;
    o.w = p0.w + p1.w + p2.w + p3.w + bv.w;
    *(float4*)(out + (size_t)i * 4) = o;
}

extern "C" void kernel_launch(void* const* d_in, const int* in_sizes, int n_in,
                              void* d_out, int out_size, void* d_ws, size_t ws_size,
                              hipStream_t stream) {
    const float* x = (const float*)d_in[0];
    const float* W = (const float*)d_in[1];
    const float* b = (const float*)d_in[2];
    float* out = (float*)d_out;

    uint8_t* WbF   = (uint8_t*)d_ws;                          // 524288 B
    float*   Ppart = (float*)((uint8_t*)d_ws + WPACK_BYTES);  // 4 * 16384*96*4 B

    wpack_kernel<<<96, 256, 0, stream>>>(W, WbF);
    mh_gemm_kernel<<<(M_ROWS / 128) * KSPLIT, 256, 0, stream>>>(x, WbF, Ppart);
    reduce_kernel<<<(M_ROWS * NH / 4) / 256, 256, 0, stream>>>(Ppart, b, out);
}